// Round 7
// baseline (123.999 us; speedup 1.0000x reference)
//
#include <hip/hip_runtime.h>
#include <math.h>

#define D_MODEL 1024
#define HEAD 64
#define SEQ 2048
#define BATCH 4

typedef _Float16 f16x4 __attribute__((ext_vector_type(4)));
typedef _Float16 f16x8 __attribute__((ext_vector_type(8)));
typedef float f32x4 __attribute__((ext_vector_type(4)));

// ---------------- prepass: wT[192][1024] fp16 from wq/wk/wv fp32 [1024][64] ---
__global__ __launch_bounds__(256) void prep_w(
    const float* __restrict__ wq, const float* __restrict__ wk,
    const float* __restrict__ wv, _Float16* __restrict__ wT)
{
    const float* w = (blockIdx.y == 0) ? wq : (blockIdx.y == 1) ? wk : wv;
    const int kbase = blockIdx.x * 64;
    __shared__ float t[64][65];
    const int tid = threadIdx.x;
    #pragma unroll
    for (int i = 0; i < 16; i++) {
        int idx = tid + i * 256;
        int kk = idx >> 6, c = idx & 63;
        t[kk][c] = w[(size_t)(kbase + kk) * 64 + c];
    }
    __syncthreads();
    #pragma unroll
    for (int i = 0; i < 16; i++) {
        int idx = tid + i * 256;
        int c = idx >> 6, kk = idx & 63;
        wT[(size_t)(blockIdx.y * 64 + c) * 1024 + kbase + kk] = (_Float16)t[kk][c];
    }
}

// ---------------- fused QKV projection: pipelined LDS relay, fp16 MFMA --------
// grid 512 x 768 thr (12 waves, 2 blocks/CU). Block: 16 rows x 192 fused cols;
// wave w owns cols [16w,16w+16). Chunk loop order: barrier -> issue wT loads
// (L2, oldest) -> issue x prefetch (HBM, youngest in vmcnt FIFO) -> MFMA from
// LDS buf[c&1] -> ds_write prefetch into buf[(c+1)&1].
// K/V epilogues write MFMA-FRAGMENT-ORDER tensors so attn needs no LDS:
//   kF: strip s=seq/16, half h=d/32: elem ((s*2+h)*64 + (seq%16) + 16*((d>>3)&3))*8 + d%8
//       -> attn's f16x8 A-frag (K[key=l16][h*32+quad*8..+8]) is a DENSE 1KB wave load.
//   vF: strip s, dt=d/16: elem ((s*4+dt)*64 + (d%16) + 16*((seq%16)/4))*4 + seq%4
//       -> attn's f16x4 A-frag (V^T[dt*16+l16][quad*4..+4]) is a DENSE 512B wave load.
__global__ __launch_bounds__(768, 6) void proj_kernel(
    const float* __restrict__ x, const _Float16* __restrict__ wT,
    const float* __restrict__ bq, const float* __restrict__ bk2,
    const float* __restrict__ bv,
    _Float16* __restrict__ q, _Float16* __restrict__ kF, _Float16* __restrict__ vF)
{
    const int tid = threadIdx.x;
    const int wave = tid >> 6;          // 0..11
    const int lane = tid & 63;
    const int l16 = lane & 15;
    const int quad = lane >> 4;
    const int row0 = blockIdx.x * 16;

    __shared__ __align__(16) _Float16 Xs[2][16][136];   // pitch 272B

    // staging: threads 0..511 each own one float4 of the 16x128 fp32 chunk
    const int srow = tid >> 5;          // 0..15 (tid<512)
    const int sc4 = tid & 31;
    const float4* xg = reinterpret_cast<const float4*>(x)
                     + (size_t)(row0 + srow) * (D_MODEL / 4) + sc4;

    const _Float16* wp = wT + (size_t)(wave * 16 + l16) * D_MODEL + quad * 8;

    // prologue: chunk 0 into buf 0
    float4 xr;
    if (tid < 512) {
        xr = xg[0];
        f16x4 h;
        h[0] = (_Float16)xr.x; h[1] = (_Float16)xr.y;
        h[2] = (_Float16)xr.z; h[3] = (_Float16)xr.w;
        *(f16x4*)&Xs[0][srow][sc4 * 4] = h;
    }

    f32x4 acc = (f32x4){0.f, 0.f, 0.f, 0.f};

    #pragma unroll 1
    for (int c = 0; c < 8; c++) {
        __syncthreads();                 // publish buf[c&1]; guard buf[(c+1)&1] reuse
        // wT loads for THIS chunk first (oldest in FIFO; L2-fast)
        f16x8 bw0 = *(const f16x8*)(wp + c * 128);
        f16x8 bw1 = *(const f16x8*)(wp + c * 128 + 32);
        f16x8 bw2 = *(const f16x8*)(wp + c * 128 + 64);
        f16x8 bw3 = *(const f16x8*)(wp + c * 128 + 96);
        // x prefetch for NEXT chunk (youngest; stays in flight through compute)
        if (c < 7 && tid < 512) xr = xg[(c + 1) * 32];
        const int bsel = c & 1;
        f16x8 aX0 = *(const f16x8*)&Xs[bsel][l16][0 * 32 + quad * 8];
        f16x8 aX1 = *(const f16x8*)&Xs[bsel][l16][1 * 32 + quad * 8];
        f16x8 aX2 = *(const f16x8*)&Xs[bsel][l16][2 * 32 + quad * 8];
        f16x8 aX3 = *(const f16x8*)&Xs[bsel][l16][3 * 32 + quad * 8];
        acc = __builtin_amdgcn_mfma_f32_16x16x32_f16(aX0, bw0, acc, 0, 0, 0);
        acc = __builtin_amdgcn_mfma_f32_16x16x32_f16(aX1, bw1, acc, 0, 0, 0);
        acc = __builtin_amdgcn_mfma_f32_16x16x32_f16(aX2, bw2, acc, 0, 0, 0);
        acc = __builtin_amdgcn_mfma_f32_16x16x32_f16(aX3, bw3, acc, 0, 0, 0);
        if (c < 7 && tid < 512) {
            f16x4 h;                     // vmcnt wait for xr lands HERE, post-compute
            h[0] = (_Float16)xr.x; h[1] = (_Float16)xr.y;
            h[2] = (_Float16)xr.z; h[3] = (_Float16)xr.w;
            *(f16x4*)&Xs[bsel ^ 1][srow][sc4 * 4] = h;
        }
    }

    // epilogue: C/D layout col=l16, row=quad*4+r; tensor choice wave-uniform
    const int g = wave * 16 + l16;       // fused col 0..191
    const int batch = row0 / SEQ;
    const int rbase = row0 + quad * 4;
    const int seq0 = row0 - batch * SEQ + quad * 4;   // in-batch seq of rows r=0..3
    if (g < 64) {
        float bias = bq[g];
        #pragma unroll
        for (int r = 0; r < 4; r++)
            q[(size_t)(rbase + r) * HEAD + g] = (_Float16)((acc[r] + bias) * 0.125f);
    } else if (g < 128) {
        const int d = g - 64;
        float bias = bk2[d];
        // kF frag-order: rows seq0+r are consecutive lanes -> elem stride 8 (16B)
        _Float16* kp = kF + (size_t)batch * (SEQ * HEAD)
                     + (size_t)(((seq0 >> 4) * 2 + (d >> 5)) * 64
                                + (seq0 & 15) + 16 * ((d >> 3) & 3)) * 8 + (d & 7);
        #pragma unroll
        for (int r = 0; r < 4; r++)
            kp[r * 8] = (_Float16)(acc[r] + bias);
    } else {
        const int d = g - 128;
        float bias = bv[d];
        f16x4 pk;
        #pragma unroll
        for (int r = 0; r < 4; r++) pk[r] = (_Float16)(acc[r] + bias);
        // vF frag-order: the 4 keys of this thread are the 4 packed elems of one lane
        _Float16* vp = vF + (size_t)batch * (SEQ * HEAD)
                     + (size_t)(((seq0 >> 4) * 4 + (d >> 4)) * 64
                                + (d & 15) + 16 * quad) * 4;
        *(f16x4*)vp = pk;
    }
}

// ---------------- flash attention: 64 queries/block, L3-traffic-halved -------
// R6 post-mortem: attn is L3-BW-bound. Every block reads its batch's full K+V
// (512KB) from Infinity Cache (proj wrote it on other XCDs; L2s flushed at
// kernel boundary): 256 blocks x 512KB = 128MB @ ~9TB/s ~= the invariant
// ~15us. Structure changes (barriers, pipeline depth, LDS removal) were all
// neutral because traffic never changed. Fix: 64 queries per block -> grid
// (32,4) = 128 blocks -> 64MB total. Per-strip compute doubles (more latency
// cover, same total FLOPs). Register-direct fragments as R6 (zero LDS in main
// loop), depth-3 named-stage pipeline (48 staging VGPR), zero barriers until
// the merge. Merge LDS: Oall[8][4][16][68] = 139KB + Lall 2KB = 141KB < 160KB,
// 1 block/CU as before. 512 thr; wave owns 64q x 256 keys (16 strips).
__global__ __launch_bounds__(512) void attn_kernel(
    const _Float16* __restrict__ q, const _Float16* __restrict__ kF,
    const _Float16* __restrict__ vF, float* __restrict__ out)
{
    const int tid = threadIdx.x;
    const int wave = tid >> 6;          // 0..7 -> key range [256w, 256w+256)
    const int lane = tid & 63;
    const int l16 = lane & 15;
    const int quad = lane >> 4;
    const int b = blockIdx.y;
    const int q0 = blockIdx.x * 64;

    __shared__ __align__(16) float Oall[8][4][16][68];   // 139264 B (merge only)
    __shared__ float Lall[8][4][16];                     // 2048 B

    // Q^T B-frags for 4 16-q tiles: n=query=l16, k=d=quad*8+j (q pre-scaled)
    f16x8 bQ00, bQ01, bQ10, bQ11, bQ20, bQ21, bQ30, bQ31;
    {
        const _Float16* qp = q + (size_t)(b * SEQ + q0 + l16) * HEAD + quad * 8;
        bQ00 = *(const f16x8*)qp;
        bQ01 = *(const f16x8*)(qp + 32);
        bQ10 = *(const f16x8*)(qp + 16 * HEAD);
        bQ11 = *(const f16x8*)(qp + 16 * HEAD + 32);
        bQ20 = *(const f16x8*)(qp + 32 * HEAD);
        bQ21 = *(const f16x8*)(qp + 32 * HEAD + 32);
        bQ30 = *(const f16x8*)(qp + 48 * HEAD);
        bQ31 = *(const f16x8*)(qp + 48 * HEAD + 32);
    }

    // frag-order bases: strip c of this wave lives at +c*1024 elems in both
    const _Float16* kgb = kF + (size_t)b * (SEQ * HEAD) + wave * 16 * 1024 + lane * 8;
    const _Float16* vgb = vF + (size_t)b * (SEQ * HEAD) + wave * 16 * 1024 + lane * 4;

    f32x4 O0[4], O1[4], O2[4], O3[4];
    #pragma unroll
    for (int dt = 0; dt < 4; dt++) {
        O0[dt] = (f32x4){0.f, 0.f, 0.f, 0.f};
        O1[dt] = (f32x4){0.f, 0.f, 0.f, 0.f};
        O2[dt] = (f32x4){0.f, 0.f, 0.f, 0.f};
        O3[dt] = (f32x4){0.f, 0.f, 0.f, 0.f};
    }
    float lp0 = 0.f, lp1 = 0.f, lp2 = 0.f, lp3 = 0.f;

    // three in-flight register stages, all indices compile-time (rule #20)
    f16x8 kr0[3], kr1[3];
    f16x4 vv0[3], vv1[3], vv2[3], vv3[3];

#define LOADS(SI, STRIP) { \
        kr0[SI] = *(const f16x8*)(kgb + (STRIP) * 1024); \
        kr1[SI] = *(const f16x8*)(kgb + (STRIP) * 1024 + 512); \
        vv0[SI] = *(const f16x4*)(vgb + (STRIP) * 1024); \
        vv1[SI] = *(const f16x4*)(vgb + (STRIP) * 1024 + 256); \
        vv2[SI] = *(const f16x4*)(vgb + (STRIP) * 1024 + 512); \
        vv3[SI] = *(const f16x4*)(vgb + (STRIP) * 1024 + 768); \
    }

    // one 16-query tile: S^T (2 MFMA) -> exp -> P-frag -> PV (4 MFMA)
#define TILE(SI, T) { \
        f32x4 s_ = __builtin_amdgcn_mfma_f32_16x16x32_f16(kr0[SI], bQ##T##0, (f32x4){0.f, 0.f, 0.f, 0.f}, 0, 0, 0); \
        s_ = __builtin_amdgcn_mfma_f32_16x16x32_f16(kr1[SI], bQ##T##1, s_, 0, 0, 0); \
        float e0_ = __expf(s_[0]), e1_ = __expf(s_[1]); \
        float e2_ = __expf(s_[2]), e3_ = __expf(s_[3]); \
        lp##T += (e0_ + e1_) + (e2_ + e3_); \
        f16x4 bP_; \
        bP_[0] = (_Float16)e0_; bP_[1] = (_Float16)e1_; \
        bP_[2] = (_Float16)e2_; bP_[3] = (_Float16)e3_; \
        O##T[0] = __builtin_amdgcn_mfma_f32_16x16x16f16(vv0[SI], bP_, O##T[0], 0, 0, 0); \
        O##T[1] = __builtin_amdgcn_mfma_f32_16x16x16f16(vv1[SI], bP_, O##T[1], 0, 0, 0); \
        O##T[2] = __builtin_amdgcn_mfma_f32_16x16x16f16(vv2[SI], bP_, O##T[2], 0, 0, 0); \
        O##T[3] = __builtin_amdgcn_mfma_f32_16x16x16f16(vv3[SI], bP_, O##T[3], 0, 0, 0); \
    }

#define COMP(SI) { TILE(SI, 0) TILE(SI, 1) TILE(SI, 2) TILE(SI, 3) }

    // iter C: consume stage C%3 (holds strip C), then refill it with strip C+3
    // (WAR on the stage regs keeps the load AFTER the consume; 2 stages in flight)
#define ITER(C) { \
        COMP((C) % 3) \
        if ((C) <= 12) LOADS((C) % 3, (C) + 3) \
    }

    LOADS(0, 0) LOADS(1, 1) LOADS(2, 2)

    ITER(0)  ITER(1)  ITER(2)  ITER(3)
    ITER(4)  ITER(5)  ITER(6)  ITER(7)
    ITER(8)  ITER(9)  ITER(10) ITER(11)
    ITER(12) ITER(13) ITER(14) ITER(15)

#undef LOADS
#undef TILE
#undef COMP
#undef ITER

    // quad-reduce l partials: lane l16 holds sum over this wave's 256 keys
    lp0 += __shfl_xor(lp0, 16);  lp0 += __shfl_xor(lp0, 32);
    lp1 += __shfl_xor(lp1, 16);  lp1 += __shfl_xor(lp1, 32);
    lp2 += __shfl_xor(lp2, 16);  lp2 += __shfl_xor(lp2, 32);
    lp3 += __shfl_xor(lp3, 16);  lp3 += __shfl_xor(lp3, 32);
    if (lane < 16) {
        Lall[wave][0][l16] = lp0;
        Lall[wave][1][l16] = lp1;
        Lall[wave][2][l16] = lp2;
        Lall[wave][3][l16] = lp3;
    }
    // O^T C-layout: row = d-in-tile = quad*4+r, col = query = l16
    #pragma unroll
    for (int dt = 0; dt < 4; dt++) {
        *(f32x4*)&Oall[wave][0][l16][dt * 16 + quad * 4] = O0[dt];
        *(f32x4*)&Oall[wave][1][l16][dt * 16 + quad * 4] = O1[dt];
        *(f32x4*)&Oall[wave][2][l16][dt * 16 + quad * 4] = O2[dt];
        *(f32x4*)&Oall[wave][3][l16][dt * 16 + quad * 4] = O3[dt];
    }
    __syncthreads();

    // merge 8 additive wave partials: 512 thr x 8 outputs (64q x 64d)
    {
        int qi = tid >> 3;               // 0..63
        int dd = (tid & 7) * 8;          // 0..56
        int t = qi >> 4, q16 = qi & 15;
        float L = 0.f;
        float a0 = 0.f, a1 = 0.f, a2 = 0.f, a3 = 0.f;
        float a4 = 0.f, a5 = 0.f, a6 = 0.f, a7 = 0.f;
        #pragma unroll
        for (int w = 0; w < 8; w++) {
            L += Lall[w][t][q16];
            const float* op = &Oall[w][t][q16][dd];
            a0 += op[0]; a1 += op[1]; a2 += op[2]; a3 += op[3];
            a4 += op[4]; a5 += op[5]; a6 += op[6]; a7 += op[7];
        }
        float inv = 1.f / L;
        float* po = out + (size_t)(b * SEQ + q0 + qi) * HEAD + dd;
        *(float4*)po = make_float4(a0 * inv, a1 * inv, a2 * inv, a3 * inv);
        *(float4*)(po + 4) = make_float4(a4 * inv, a5 * inv, a6 * inv, a7 * inv);
    }
}

extern "C" void kernel_launch(void* const* d_in, const int* in_sizes, int n_in,
                              void* d_out, int out_size, void* d_ws, size_t ws_size,
                              hipStream_t stream) {
    const float* x  = (const float*)d_in[0];
    const float* wq = (const float*)d_in[1];
    const float* bq = (const float*)d_in[2];
    const float* wk = (const float*)d_in[3];
    const float* bk = (const float*)d_in[4];
    const float* wv = (const float*)d_in[5];
    const float* bv = (const float*)d_in[6];
    float* out = (float*)d_out;

    const size_t proj_elems = (size_t)BATCH * SEQ * HEAD;  // 524288
    _Float16* qh = (_Float16*)d_ws;
    _Float16* kFh = qh + proj_elems;
    _Float16* vFh = kFh + proj_elems;  // frag-order, exactly proj_elems elems each
    _Float16* wT = vFh + proj_elems;   // 192*1024 elems

    prep_w<<<dim3(16, 3), 256, 0, stream>>>(wq, wk, wv, wT);
    proj_kernel<<<dim3(BATCH * SEQ / 16), 768, 0, stream>>>(x, wT, bq, bk, bv, qh, kFh, vFh);
    attn_kernel<<<dim3(SEQ / 64, BATCH), 512, 0, stream>>>(qh, kFh, vFh, out);
}

// Round 8
// 105.842 us; speedup vs baseline: 1.1716x; 1.1716x over previous
//
#include <hip/hip_runtime.h>
#include <math.h>

#define D_MODEL 1024
#define HEAD 64
#define SEQ 2048
#define BATCH 4

typedef _Float16 f16x4 __attribute__((ext_vector_type(4)));
typedef _Float16 f16x8 __attribute__((ext_vector_type(8)));
typedef float f32x4 __attribute__((ext_vector_type(4)));

// ---------------- prepass: wT[192][1024] fp16 from wq/wk/wv fp32 [1024][64] ---
__global__ __launch_bounds__(256) void prep_w(
    const float* __restrict__ wq, const float* __restrict__ wk,
    const float* __restrict__ wv, _Float16* __restrict__ wT)
{
    const float* w = (blockIdx.y == 0) ? wq : (blockIdx.y == 1) ? wk : wv;
    const int kbase = blockIdx.x * 64;
    __shared__ float t[64][65];
    const int tid = threadIdx.x;
    #pragma unroll
    for (int i = 0; i < 16; i++) {
        int idx = tid + i * 256;
        int kk = idx >> 6, c = idx & 63;
        t[kk][c] = w[(size_t)(kbase + kk) * 64 + c];
    }
    __syncthreads();
    #pragma unroll
    for (int i = 0; i < 16; i++) {
        int idx = tid + i * 256;
        int c = idx >> 6, kk = idx & 63;
        wT[(size_t)(blockIdx.y * 64 + c) * 1024 + kbase + kk] = (_Float16)t[kk][c];
    }
}

// ---------------- fused QKV projection: 32 rows/block, pipelined LDS relay ---
// R7 round: proj was the untouched term (~12us vs ~6us floor); its dominant
// cost was wT L2 re-reads: 512 blocks x 384KB = 192MB. Now 32 rows per block
// -> 256 blocks (1/CU, 12 waves) -> 96MB wT traffic, 8 MFMA/chunk/wave
// (double per-chunk compute per barrier). Staging threads (tid<512) each own
// one float4 in BOTH row-tiles. Chunk loop order unchanged: barrier -> wT
// loads (L2, oldest) -> x prefetch (HBM, youngest) -> MFMA from buf[c&1] ->
// ds_write into buf^1 (prefetch crosses compute, not the barrier).
// K/V epilogues write MFMA-FRAGMENT-ORDER tensors so attn needs no LDS:
//   kF: strip s=seq/16, half h=d/32: elem ((s*2+h)*64 + (seq%16) + 16*((d>>3)&3))*8 + d%8
//   vF: strip s, dt=d/16: elem ((s*4+dt)*64 + (d%16) + 16*((seq%16)/4))*4 + seq%4
__global__ __launch_bounds__(768, 3) void proj_kernel(
    const float* __restrict__ x, const _Float16* __restrict__ wT,
    const float* __restrict__ bq, const float* __restrict__ bk2,
    const float* __restrict__ bv,
    _Float16* __restrict__ q, _Float16* __restrict__ kF, _Float16* __restrict__ vF)
{
    const int tid = threadIdx.x;
    const int wave = tid >> 6;          // 0..11
    const int lane = tid & 63;
    const int l16 = lane & 15;
    const int quad = lane >> 4;
    const int row0 = blockIdx.x * 32;

    __shared__ __align__(16) _Float16 Xs[2][32][136];   // pitch 272B, 17408B

    // staging: threads 0..511 own one float4 in each of the two 16-row tiles
    const int srow = tid >> 5;          // 0..15 (tid<512)
    const int sc4 = tid & 31;
    const float4* xg0 = reinterpret_cast<const float4*>(x)
                      + (size_t)(row0 + srow) * (D_MODEL / 4) + sc4;
    const float4* xg1 = xg0 + (size_t)16 * (D_MODEL / 4);

    const _Float16* wp = wT + (size_t)(wave * 16 + l16) * D_MODEL + quad * 8;

    // prologue: chunk 0 into buf 0
    float4 xr0, xr1;
    if (tid < 512) {
        xr0 = xg0[0];
        xr1 = xg1[0];
        f16x4 h0, h1;
        h0[0] = (_Float16)xr0.x; h0[1] = (_Float16)xr0.y;
        h0[2] = (_Float16)xr0.z; h0[3] = (_Float16)xr0.w;
        h1[0] = (_Float16)xr1.x; h1[1] = (_Float16)xr1.y;
        h1[2] = (_Float16)xr1.z; h1[3] = (_Float16)xr1.w;
        *(f16x4*)&Xs[0][srow][sc4 * 4] = h0;
        *(f16x4*)&Xs[0][srow + 16][sc4 * 4] = h1;
    }

    f32x4 acc0 = (f32x4){0.f, 0.f, 0.f, 0.f};
    f32x4 acc1 = (f32x4){0.f, 0.f, 0.f, 0.f};

    #pragma unroll 1
    for (int c = 0; c < 8; c++) {
        __syncthreads();                 // publish buf[c&1]; guard buf[(c+1)&1] reuse
        // wT loads for THIS chunk first (oldest in FIFO; L2-fast)
        f16x8 bw0 = *(const f16x8*)(wp + c * 128);
        f16x8 bw1 = *(const f16x8*)(wp + c * 128 + 32);
        f16x8 bw2 = *(const f16x8*)(wp + c * 128 + 64);
        f16x8 bw3 = *(const f16x8*)(wp + c * 128 + 96);
        // x prefetch for NEXT chunk (youngest; stays in flight through compute)
        if (c < 7 && tid < 512) {
            xr0 = xg0[(c + 1) * 32];
            xr1 = xg1[(c + 1) * 32];
        }
        const int bsel = c & 1;
        // row-tile 0 (rows l16)
        f16x8 aX0 = *(const f16x8*)&Xs[bsel][l16][0 * 32 + quad * 8];
        f16x8 aX1 = *(const f16x8*)&Xs[bsel][l16][1 * 32 + quad * 8];
        f16x8 aX2 = *(const f16x8*)&Xs[bsel][l16][2 * 32 + quad * 8];
        f16x8 aX3 = *(const f16x8*)&Xs[bsel][l16][3 * 32 + quad * 8];
        acc0 = __builtin_amdgcn_mfma_f32_16x16x32_f16(aX0, bw0, acc0, 0, 0, 0);
        acc0 = __builtin_amdgcn_mfma_f32_16x16x32_f16(aX1, bw1, acc0, 0, 0, 0);
        acc0 = __builtin_amdgcn_mfma_f32_16x16x32_f16(aX2, bw2, acc0, 0, 0, 0);
        acc0 = __builtin_amdgcn_mfma_f32_16x16x32_f16(aX3, bw3, acc0, 0, 0, 0);
        // row-tile 1 (rows 16+l16)
        f16x8 aY0 = *(const f16x8*)&Xs[bsel][16 + l16][0 * 32 + quad * 8];
        f16x8 aY1 = *(const f16x8*)&Xs[bsel][16 + l16][1 * 32 + quad * 8];
        f16x8 aY2 = *(const f16x8*)&Xs[bsel][16 + l16][2 * 32 + quad * 8];
        f16x8 aY3 = *(const f16x8*)&Xs[bsel][16 + l16][3 * 32 + quad * 8];
        acc1 = __builtin_amdgcn_mfma_f32_16x16x32_f16(aY0, bw0, acc1, 0, 0, 0);
        acc1 = __builtin_amdgcn_mfma_f32_16x16x32_f16(aY1, bw1, acc1, 0, 0, 0);
        acc1 = __builtin_amdgcn_mfma_f32_16x16x32_f16(aY2, bw2, acc1, 0, 0, 0);
        acc1 = __builtin_amdgcn_mfma_f32_16x16x32_f16(aY3, bw3, acc1, 0, 0, 0);
        if (c < 7 && tid < 512) {
            f16x4 h0, h1;                // vmcnt wait for xr lands HERE, post-compute
            h0[0] = (_Float16)xr0.x; h0[1] = (_Float16)xr0.y;
            h0[2] = (_Float16)xr0.z; h0[3] = (_Float16)xr0.w;
            h1[0] = (_Float16)xr1.x; h1[1] = (_Float16)xr1.y;
            h1[2] = (_Float16)xr1.z; h1[3] = (_Float16)xr1.w;
            *(f16x4*)&Xs[bsel ^ 1][srow][sc4 * 4] = h0;
            *(f16x4*)&Xs[bsel ^ 1][srow + 16][sc4 * 4] = h1;
        }
    }

    // epilogue: C/D layout col=l16, row=quad*4+r; two row-tiles; choice wave-uniform
    const int g = wave * 16 + l16;       // fused col 0..191
    const int batch = row0 / SEQ;        // 32-row blocks never straddle batches
    #pragma unroll
    for (int rt = 0; rt < 2; rt++) {
        const f32x4 acc = rt ? acc1 : acc0;
        const int rbase = row0 + rt * 16 + quad * 4;
        const int seq0 = rbase - batch * SEQ;          // in-batch seq of rows r=0..3
        if (g < 64) {
            float bias = bq[g];
            #pragma unroll
            for (int r = 0; r < 4; r++)
                q[(size_t)(rbase + r) * HEAD + g] = (_Float16)((acc[r] + bias) * 0.125f);
        } else if (g < 128) {
            const int d = g - 64;
            float bias = bk2[d];
            // kF frag-order: rows seq0+r are consecutive lanes -> elem stride 8 (16B)
            _Float16* kp = kF + (size_t)batch * (SEQ * HEAD)
                         + (size_t)(((seq0 >> 4) * 2 + (d >> 5)) * 64
                                    + (seq0 & 15) + 16 * ((d >> 3) & 3)) * 8 + (d & 7);
            #pragma unroll
            for (int r = 0; r < 4; r++)
                kp[r * 8] = (_Float16)(acc[r] + bias);
        } else {
            const int d = g - 128;
            float bias = bv[d];
            f16x4 pk;
            #pragma unroll
            for (int r = 0; r < 4; r++) pk[r] = (_Float16)(acc[r] + bias);
            // vF frag-order: the 4 keys of this thread are the 4 packed elems of one lane
            _Float16* vp = vF + (size_t)batch * (SEQ * HEAD)
                         + (size_t)(((seq0 >> 4) * 4 + (d >> 4)) * 64
                                    + (d & 15) + 16 * quad) * 4;
            *(f16x4*)vp = pk;
        }
    }
}

// ---------------- flash attention: register-direct fragments, NO LDS relay ---
// Reverted to the R6 version (best measured): 32q/block, grid (64,4) = 256
// blocks (1/CU), zero LDS in the main loop (proj wrote kF/vF in MFMA-fragment
// order -> dense lane-contiguous global loads straight into MFMA A-regs),
// depth-4 named-stage register pipeline, zero barriers until the Oall/Lall
// merge. R7's 64q variant regressed (128 blocks left half the CUs idle).
__global__ __launch_bounds__(512) void attn_kernel(
    const _Float16* __restrict__ q, const _Float16* __restrict__ kF,
    const _Float16* __restrict__ vF, float* __restrict__ out)
{
    const int tid = threadIdx.x;
    const int wave = tid >> 6;          // 0..7 -> key range [256w, 256w+256)
    const int lane = tid & 63;
    const int l16 = lane & 15;
    const int quad = lane >> 4;
    const int b = blockIdx.y;
    const int q0 = blockIdx.x * 32;

    __shared__ __align__(16) float Oall[8][2][16][68];   // 69632 B (merge only)
    __shared__ float Lall[8][2][16];

    // Q^T B-frags for both 16-q tiles: n=query=l16, k=d=quad*8+j (q pre-scaled)
    f16x8 bQ00, bQ01, bQ10, bQ11;
    {
        const _Float16* qp = q + (size_t)(b * SEQ + q0 + l16) * HEAD + quad * 8;
        bQ00 = *(const f16x8*)qp;
        bQ01 = *(const f16x8*)(qp + 32);
        bQ10 = *(const f16x8*)(qp + 16 * HEAD);
        bQ11 = *(const f16x8*)(qp + 16 * HEAD + 32);
    }

    // frag-order bases: strip c of this wave lives at +c*1024 elems in both
    const _Float16* kgb = kF + (size_t)b * (SEQ * HEAD) + wave * 16 * 1024 + lane * 8;
    const _Float16* vgb = vF + (size_t)b * (SEQ * HEAD) + wave * 16 * 1024 + lane * 4;

    f32x4 O0[4], O1[4];
    #pragma unroll
    for (int dt = 0; dt < 4; dt++) {
        O0[dt] = (f32x4){0.f, 0.f, 0.f, 0.f};
        O1[dt] = (f32x4){0.f, 0.f, 0.f, 0.f};
    }
    float lp0 = 0.f, lp1 = 0.f;

    // four in-flight register stages, all indices compile-time (rule #20)
    f16x8 kr0[4], kr1[4];
    f16x4 vv0[4], vv1[4], vv2[4], vv3[4];

#define LOADS(SI, STRIP) { \
        kr0[SI] = *(const f16x8*)(kgb + (STRIP) * 1024); \
        kr1[SI] = *(const f16x8*)(kgb + (STRIP) * 1024 + 512); \
        vv0[SI] = *(const f16x4*)(vgb + (STRIP) * 1024); \
        vv1[SI] = *(const f16x4*)(vgb + (STRIP) * 1024 + 256); \
        vv2[SI] = *(const f16x4*)(vgb + (STRIP) * 1024 + 512); \
        vv3[SI] = *(const f16x4*)(vgb + (STRIP) * 1024 + 768); \
    }

#define COMP(SI) { \
        f32x4 s0 = __builtin_amdgcn_mfma_f32_16x16x32_f16(kr0[SI], bQ00, (f32x4){0.f, 0.f, 0.f, 0.f}, 0, 0, 0); \
        s0 = __builtin_amdgcn_mfma_f32_16x16x32_f16(kr1[SI], bQ01, s0, 0, 0, 0); \
        f32x4 s1 = __builtin_amdgcn_mfma_f32_16x16x32_f16(kr0[SI], bQ10, (f32x4){0.f, 0.f, 0.f, 0.f}, 0, 0, 0); \
        s1 = __builtin_amdgcn_mfma_f32_16x16x32_f16(kr1[SI], bQ11, s1, 0, 0, 0); \
        float p00 = __expf(s0[0]), p01 = __expf(s0[1]); \
        float p02 = __expf(s0[2]), p03 = __expf(s0[3]); \
        float p10 = __expf(s1[0]), p11 = __expf(s1[1]); \
        float p12 = __expf(s1[2]), p13 = __expf(s1[3]); \
        lp0 += (p00 + p01) + (p02 + p03); \
        lp1 += (p10 + p11) + (p12 + p13); \
        f16x4 bP0, bP1; \
        bP0[0] = (_Float16)p00; bP0[1] = (_Float16)p01; \
        bP0[2] = (_Float16)p02; bP0[3] = (_Float16)p03; \
        bP1[0] = (_Float16)p10; bP1[1] = (_Float16)p11; \
        bP1[2] = (_Float16)p12; bP1[3] = (_Float16)p13; \
        O0[0] = __builtin_amdgcn_mfma_f32_16x16x16f16(vv0[SI], bP0, O0[0], 0, 0, 0); \
        O1[0] = __builtin_amdgcn_mfma_f32_16x16x16f16(vv0[SI], bP1, O1[0], 0, 0, 0); \
        O0[1] = __builtin_amdgcn_mfma_f32_16x16x16f16(vv1[SI], bP0, O0[1], 0, 0, 0); \
        O1[1] = __builtin_amdgcn_mfma_f32_16x16x16f16(vv1[SI], bP1, O1[1], 0, 0, 0); \
        O0[2] = __builtin_amdgcn_mfma_f32_16x16x16f16(vv2[SI], bP0, O0[2], 0, 0, 0); \
        O1[2] = __builtin_amdgcn_mfma_f32_16x16x16f16(vv2[SI], bP1, O1[2], 0, 0, 0); \
        O0[3] = __builtin_amdgcn_mfma_f32_16x16x16f16(vv3[SI], bP0, O0[3], 0, 0, 0); \
        O1[3] = __builtin_amdgcn_mfma_f32_16x16x16f16(vv3[SI], bP1, O1[3], 0, 0, 0); \
    }

    // iter C: consume stage C%4, then refill it with strip C+4 (WAR on the
    // stage regs keeps the load AFTER the consume; 3 stages stay in flight)
#define ITER(C) { \
        COMP((C) & 3) \
        if ((C) <= 11) LOADS((C) & 3, (C) + 4) \
    }

    LOADS(0, 0) LOADS(1, 1) LOADS(2, 2) LOADS(3, 3)

    ITER(0)  ITER(1)  ITER(2)  ITER(3)
    ITER(4)  ITER(5)  ITER(6)  ITER(7)
    ITER(8)  ITER(9)  ITER(10) ITER(11)
    ITER(12) ITER(13) ITER(14) ITER(15)

#undef LOADS
#undef COMP
#undef ITER

    // quad-reduce l partials: lane l16 holds sum over this wave's 256 keys
    lp0 += __shfl_xor(lp0, 16);
    lp0 += __shfl_xor(lp0, 32);
    lp1 += __shfl_xor(lp1, 16);
    lp1 += __shfl_xor(lp1, 32);
    if (lane < 16) {
        Lall[wave][0][l16] = lp0;
        Lall[wave][1][l16] = lp1;
    }
    // O^T C-layout: row = d-in-tile = quad*4+r, col = query = l16
    #pragma unroll
    for (int dt = 0; dt < 4; dt++) {
        *(f32x4*)&Oall[wave][0][l16][dt * 16 + quad * 4] = O0[dt];
        *(f32x4*)&Oall[wave][1][l16][dt * 16 + quad * 4] = O1[dt];
    }
    __syncthreads();

    // merge 8 additive wave partials: 512 thr x 4 outputs (32q x 64d)
    {
        int qi = tid >> 4;               // 0..31
        int dd = (tid & 15) * 4;         // 0..60
        int t = qi >> 4, q16 = qi & 15;
        float L = 0.f, a0 = 0.f, a1 = 0.f, a2 = 0.f, a3 = 0.f;
        #pragma unroll
        for (int w = 0; w < 8; w++) {
            L += Lall[w][t][q16];
            const float* op = &Oall[w][t][q16][dd];
            a0 += op[0]; a1 += op[1]; a2 += op[2]; a3 += op[3];
        }
        float inv = 1.f / L;
        float4 res = make_float4(a0 * inv, a1 * inv, a2 * inv, a3 * inv);
        *(float4*)(out + (size_t)(b * SEQ + q0 + qi) * HEAD + dd) = res;
    }
}

extern "C" void kernel_launch(void* const* d_in, const int* in_sizes, int n_in,
                              void* d_out, int out_size, void* d_ws, size_t ws_size,
                              hipStream_t stream) {
    const float* x  = (const float*)d_in[0];
    const float* wq = (const float*)d_in[1];
    const float* bq = (const float*)d_in[2];
    const float* wk = (const float*)d_in[3];
    const float* bk = (const float*)d_in[4];
    const float* wv = (const float*)d_in[5];
    const float* bv = (const float*)d_in[6];
    float* out = (float*)d_out;

    const size_t proj_elems = (size_t)BATCH * SEQ * HEAD;  // 524288
    _Float16* qh = (_Float16*)d_ws;
    _Float16* kFh = qh + proj_elems;
    _Float16* vFh = kFh + proj_elems;  // frag-order, exactly proj_elems elems each
    _Float16* wT = vFh + proj_elems;   // 192*1024 elems

    prep_w<<<dim3(16, 3), 256, 0, stream>>>(wq, wk, wv, wT);
    proj_kernel<<<dim3(BATCH * SEQ / 32), 768, 0, stream>>>(x, wT, bq, bk, bv, qh, kFh, vFh);
    attn_kernel<<<dim3(SEQ / 32, BATCH), 512, 0, stream>>>(qh, kFh, vFh, out);
}